// Round 2
// baseline (131.734 us; speedup 1.0000x reference)
//
#include <hip/hip_runtime.h>
#include <cmath>

// Static problem config (matches reference)
#define RB 20
#define RA 19
#define NPT (RB*RA)
#define DZ 25
#define DIN 9
#define MULT 128
#define CH 128

// ---------------------------------------------------------------------------
// Host: transposed dense real-Gaunt table Gt[d1*9+d2][28] in fp64 from the
// reference's own quadrature (exact bilinear identity). Cols 25..27 zero pads.
// NOTE (R1 post-mortem): the captured hipMemcpyAsync of this 9 KB table is
// ~free at replay (graph snapshots the host buffer). The ~57us gap between
// bench dur_us and kernel dur_us is fixed harness overhead (reset memsets),
// NOT this copy. Keep the host build; do not device-build.
static void host_build_gaunt(float* out /* 81*28, zero-padded */) {
    const double PI = 3.14159265358979323846;
    double xq[RB], wq[RB];
    for (int i = 0; i < RB; ++i) {
        double x = cos(PI * (i + 0.75) / (RB + 0.5));
        double dp = 0.0;
        for (int it = 0; it < 100; ++it) {
            double p0 = 1.0, p1 = x;
            for (int k = 2; k <= RB; ++k) {
                double p2 = ((2.0*k - 1.0)*x*p1 - (k - 1.0)*p0) / (double)k;
                p0 = p1; p1 = p2;
            }
            dp = RB * (x*p1 - p0) / (x*x - 1.0);
            double dx = p1 / dp;
            x -= dx;
            if (fabs(dx) < 1e-15) break;
        }
        {
            double p0 = 1.0, p1 = x;
            for (int k = 2; k <= RB; ++k) {
                double p2 = ((2.0*k - 1.0)*x*p1 - (k - 1.0)*p0) / (double)k;
                p0 = p1; p1 = p2;
            }
            dp = RB * (x*p1 - p0) / (x*x - 1.0);
        }
        xq[i] = x;
        wq[i] = 2.0 / ((1.0 - x*x)*dp*dp);
    }
    static double Y[DZ][NPT];
    static double qws[NPT];
    for (int b = 0; b < RB; ++b) {
        double ct = xq[b], st = sqrt(fmax(0.0, 1.0 - ct*ct));
        double P[5][5]; double pmm = 1.0;
        for (int m = 0; m <= 4; ++m) {
            if (m > 0) pmm *= -(2.0*m - 1.0) * st;
            P[m][m] = pmm;
            if (m < 4) {
                double pp = pmm, pc = ct*(2.0*m + 1.0)*pmm;
                P[m+1][m] = pc;
                for (int l = m + 2; l <= 4; ++l) {
                    double pn = ((2.0*l - 1.0)*ct*pc - (double)(l + m - 1)*pp) / (double)(l - m);
                    P[l][m] = pn; pp = pc; pc = pn;
                }
            }
        }
        for (int a = 0; a < RA; ++a) {
            int pt = b*RA + a;
            qws[pt] = wq[b] * (2.0*PI/(double)RA);
            double alpha = 2.0*PI*(double)a/(double)RA;
            for (int l = 0; l <= 4; ++l)
                for (int m = -l; m <= l; ++m) {
                    int am = m < 0 ? -m : m;
                    double fr = 1.0;
                    for (int i = l - am + 1; i <= l + am; ++i) fr *= (double)i;
                    double nlm = sqrt((2.0*l + 1.0) / (4.0*PI) / fr);
                    double ang = (m == 0) ? 1.0
                               : (m > 0 ? sqrt(2.0)*cos(am*alpha) : sqrt(2.0)*sin(am*alpha));
                    Y[l*l + l + m][pt] = nlm * P[l][am] * ang;
                }
        }
    }
    for (int pr = 0; pr < 81; ++pr) {
        int d1 = pr / 9, d2 = pr % 9;
        for (int d = 0; d < DZ; ++d) {
            double s = 0.0;
            for (int p = 0; p < NPT; ++p)
                s += Y[d][p] * Y[d1][p] * Y[d2][p] * qws[p];
            out[pr*28 + d] = (float)s;
        }
    }
}

// ---------------------------------------------------------------------------
// Stage D helper: wave owns l-aligned d-range [D0,D0+ND) (wz_l read once per
// block); lane owns e=lane and e+64; both nodes. z read as float4 broadcasts.
// c0 unrolled by 8 (16 wz loads in flight) to cover L2 latency; per-acc fma
// order identical to the unroll-4 version (same (c0,k) sequence) -> bit-exact.
template<int D0, int ND>
__device__ __forceinline__ void d_tile(const float* sZ, const float* __restrict__ wz,
                                       float* sOut, int lane) {
    const float s128 = 0.08838834764831845f;
    float acc[ND * 4];
    #pragma unroll
    for (int i = 0; i < ND * 4; ++i) acc[i] = 0.f;
    for (int c0 = 0; c0 < CH; c0 += 8) {
        #pragma unroll
        for (int i = 0; i < ND; ++i) {
            const int d = D0 + i;
            const int l = (d == 0) ? 0 : (d < 4) ? 1 : (d < 9) ? 2 : (d < 16) ? 3 : 4;
            float4 z0a = *(const float4*)(sZ + d * 128 + c0);            // node0
            float4 z0b = *(const float4*)(sZ + d * 128 + c0 + 4);
            float4 z1a = *(const float4*)(sZ + (25 + d) * 128 + c0);     // node1
            float4 z1b = *(const float4*)(sZ + (25 + d) * 128 + c0 + 4);
            float wa[8], wb[8];
            #pragma unroll
            for (int k = 0; k < 8; ++k) {                 // CSE'd across same-l i
                wa[k] = wz[l * 16384 + (c0 + k) * 128 + lane];
                wb[k] = wz[l * 16384 + (c0 + k) * 128 + lane + 64];
            }
            #pragma unroll
            for (int k = 0; k < 8; ++k) {
                float zc0 = (k == 0) ? z0a.x : (k == 1) ? z0a.y : (k == 2) ? z0a.z :
                            (k == 3) ? z0a.w : (k == 4) ? z0b.x : (k == 5) ? z0b.y :
                            (k == 6) ? z0b.z : z0b.w;
                float zc1 = (k == 0) ? z1a.x : (k == 1) ? z1a.y : (k == 2) ? z1a.z :
                            (k == 3) ? z1a.w : (k == 4) ? z1b.x : (k == 5) ? z1b.y :
                            (k == 6) ? z1b.z : z1b.w;
                acc[i*4+0] = fmaf(zc0, wa[k], acc[i*4+0]);
                acc[i*4+1] = fmaf(zc0, wb[k], acc[i*4+1]);
                acc[i*4+2] = fmaf(zc1, wa[k], acc[i*4+2]);
                acc[i*4+3] = fmaf(zc1, wb[k], acc[i*4+3]);
            }
        }
    }
    #pragma unroll
    for (int i = 0; i < ND; ++i) {
        sOut[(lane) * 25 + D0 + i]            = acc[i*4+0] * s128;
        sOut[(lane + 64) * 25 + D0 + i]       = acc[i*4+1] * s128;
        sOut[(128 + lane) * 25 + D0 + i]      = acc[i*4+2] * s128;
        sOut[(128 + lane + 64) * 25 + D0 + i] = acc[i*4+3] * s128;
    }
}

// ---------------------------------------------------------------------------
// Fully fused, 2 nodes per block, z in LDS. 256 threads (proven R0 structure;
// the 512-thread split doubled w/G fetch instructions and regressed).
// R2 changes vs R0: (1) sG gets its own LDS region, loaded during stage A
// (one fewer barrier, G fetch overlapped with x/y fetch); (2) stage A loads
// hoisted to registers before any LDS write; (3) stages B and D unrolled 8x
// on the reduction dim for VMEM latency hiding. Arithmetic order per output
// unchanged -> bit-identical results.
__global__ __launch_bounds__(256, 2) void gaunt_fused(
    const float* __restrict__ xg, const float* __restrict__ yg,
    const float* __restrict__ wxg, const float* __restrict__ wyg,
    const float* __restrict__ wzg, float* __restrict__ outg,
    const float* __restrict__ gGt) {

    // LDS pool (floats), 17884 = 71536 B (2 blocks/CU: 143072 <= 163840):
    //  sZ   [0,     6400)  z [n][dz][c]            (stages C/D)
    //  sXY  [6400, 11008)  x,y transposed          (stages A/B)
    //  sOut [6400, 12800)  out [n][e][25]          (stages D/E, after C)
    //  sXc  [11008,15616)  xc [side][d][n][c]      (stages B/C)
    //  sG   [15616,17884)  Gaunt table             (loaded in A, used in C)
    __shared__ __align__(16) float pool[17884];
    float* sZ   = pool;
    float* sXY  = pool + 6400;
    float* sOut = pool + 6400;
    float* sXc  = pool + 11008;
    float* sG   = pool + 15616;

    const int tid  = threadIdx.x;
    const int b    = blockIdx.x;
    const int lane = tid & 63;
    const int wave = __builtin_amdgcn_readfirstlane(tid >> 6);
    const float s128 = 0.08838834764831845f;   // 1/sqrt(128)

    // Stage A: load x,y for nodes 2b,2b+1 AND the Gaunt table; all global
    // loads issued before any LDS write so vmcnt waits overlap.
    {
        const float4* xs = (const float4*)(xg + 2 * b * 1152);
        const float4* ys = (const float4*)(yg + 2 * b * 1152);
        const float4* gt4 = (const float4*)gGt;
        float4 va[5];
        #pragma unroll
        for (int t = 0; t < 5; ++t) {
            int i = tid + t * 256;
            if (i < 1152) va[t] = (i < 576) ? xs[i] : ys[i - 576];
        }
        float4 ga0 = gt4[tid];
        float4 ga1 = gt4[tid + 256];
        float4 ga2;
        if (tid < 55) ga2 = gt4[tid + 512];

        #pragma unroll
        for (int t = 0; t < 5; ++t) {
            int i = tid + t * 256;
            if (i < 1152) {
                float4 v = va[t];
                int r = (i < 576) ? i : i - 576;
                int base = (i < 576) ? 0 : 2304;
                int j0 = r * 4;
                #pragma unroll
                for (int k = 0; k < 4; ++k) {
                    int j = j0 + k;
                    int n = j / 1152;
                    int jj = j - n * 1152;
                    int m = jj / 9, d = jj - 9 * m;
                    float val = (k == 0) ? v.x : (k == 1) ? v.y : (k == 2) ? v.z : v.w;
                    sXY[base + n * 1152 + d * 128 + m] = val;
                }
            }
        }
        ((float4*)sG)[tid]       = ga0;
        ((float4*)sG)[tid + 256] = ga1;
        if (tid < 55) ((float4*)sG)[tid + 512] = ga2;
    }
    __syncthreads();

    // Stage B: linear_in. wave=(side,chalf), lane owns one c; both nodes.
    // m0 unrolled by 8: 24 w-loads in flight per iter. Per-acc fma order
    // identical to unroll-4 (same (m0,k) sequence).
    {
        const int side = wave >> 1, ch = wave & 1;
        const int c = ch * 64 + lane;
        const float* wb = side ? wyg : wxg;
        const float* xb = sXY + side * 2304;   // [n][d*128+m]
        float acc[18];                          // [d][n]
        #pragma unroll
        for (int i = 0; i < 18; ++i) acc[i] = 0.f;
        for (int m0 = 0; m0 < MULT; m0 += 8) {
            float w0[8], w1[8], w2[8];
            #pragma unroll
            for (int k = 0; k < 8; ++k) {
                w0[k] = wb[(m0 + k) * 128 + c];
                w1[k] = wb[16384 + (m0 + k) * 128 + c];
                w2[k] = wb[32768 + (m0 + k) * 128 + c];
            }
            #pragma unroll
            for (int d = 0; d < 9; ++d) {
                const float* wl = (d == 0) ? w0 : (d < 4) ? w1 : w2;
                float4 x0a = *(const float4*)(xb + d * 128 + m0);
                float4 x0b = *(const float4*)(xb + d * 128 + m0 + 4);
                float4 x1a = *(const float4*)(xb + 1152 + d * 128 + m0);
                float4 x1b = *(const float4*)(xb + 1152 + d * 128 + m0 + 4);
                acc[d*2+0] = fmaf(x0a.x, wl[0], acc[d*2+0]);
                acc[d*2+0] = fmaf(x0a.y, wl[1], acc[d*2+0]);
                acc[d*2+0] = fmaf(x0a.z, wl[2], acc[d*2+0]);
                acc[d*2+0] = fmaf(x0a.w, wl[3], acc[d*2+0]);
                acc[d*2+0] = fmaf(x0b.x, wl[4], acc[d*2+0]);
                acc[d*2+0] = fmaf(x0b.y, wl[5], acc[d*2+0]);
                acc[d*2+0] = fmaf(x0b.z, wl[6], acc[d*2+0]);
                acc[d*2+0] = fmaf(x0b.w, wl[7], acc[d*2+0]);
                acc[d*2+1] = fmaf(x1a.x, wl[0], acc[d*2+1]);
                acc[d*2+1] = fmaf(x1a.y, wl[1], acc[d*2+1]);
                acc[d*2+1] = fmaf(x1a.z, wl[2], acc[d*2+1]);
                acc[d*2+1] = fmaf(x1a.w, wl[3], acc[d*2+1]);
                acc[d*2+1] = fmaf(x1b.x, wl[4], acc[d*2+1]);
                acc[d*2+1] = fmaf(x1b.y, wl[5], acc[d*2+1]);
                acc[d*2+1] = fmaf(x1b.z, wl[6], acc[d*2+1]);
                acc[d*2+1] = fmaf(x1b.w, wl[7], acc[d*2+1]);
            }
        }
        #pragma unroll
        for (int d = 0; d < 9; ++d) {
            sXc[((side * 9 + d) * 2 + 0) * 128 + c] = acc[d*2+0] * s128;
            sXc[((side * 9 + d) * 2 + 1) * 128 + c] = acc[d*2+1] * s128;
        }
    }
    __syncthreads();

    // Stage C: z[n][dz][c] = sum_{d1,d2} G[dz][d1,d2] xc[d1][c] yc[d2][c]
    // halves split 12/13 so both G-row offsets (0 and 12 floats = 48 B) are
    // 16B-aligned: 3x ds_read_b128 + 1x b32 per (d1,d2) (all broadcasts).
    {
        const int c = tid & 127;
        const int half = __builtin_amdgcn_readfirstlane(tid >> 7);
        const int dz0 = half ? 12 : 0;
        float xr0[9], xr1[9], yr0[9], yr1[9];
        #pragma unroll
        for (int d = 0; d < 9; ++d) {
            xr0[d] = sXc[(d * 2 + 0) * 128 + c];
            xr1[d] = sXc[(d * 2 + 1) * 128 + c];
            yr0[d] = sXc[((9 + d) * 2 + 0) * 128 + c];
            yr1[d] = sXc[((9 + d) * 2 + 1) * 128 + c];
        }
        float a0[13], a1[13];
        #pragma unroll
        for (int i = 0; i < 13; ++i) { a0[i] = 0.f; a1[i] = 0.f; }
        for (int d1 = 0; d1 < 9; ++d1) {
            #pragma unroll
            for (int d2 = 0; d2 < 9; ++d2) {
                float p0 = xr0[d1] * yr0[d2];
                float p1 = xr1[d1] * yr1[d2];
                const float* gt = sG + (d1 * 9 + d2) * 28 + dz0;   // 16B-aligned
                float4 g0 = *(const float4*)gt;
                float4 g1 = *(const float4*)(gt + 4);
                float4 g2 = *(const float4*)(gt + 8);
                float  g3 = gt[12];            // half0: unused d12 dup; half1: dz24
                float gv[13] = {g0.x,g0.y,g0.z,g0.w, g1.x,g1.y,g1.z,g1.w,
                                g2.x,g2.y,g2.z,g2.w, g3};
                #pragma unroll
                for (int i = 0; i < 13; ++i) {
                    a0[i] = fmaf(p0, gv[i], a0[i]);
                    a1[i] = fmaf(p1, gv[i], a1[i]);
                }
            }
        }
        if (half == 0) {
            #pragma unroll
            for (int i = 0; i < 12; ++i) {      // dz 0..11 (a*[12] discarded)
                sZ[i * 128 + c]        = a0[i];
                sZ[(25 + i) * 128 + c] = a1[i];
            }
        } else {
            #pragma unroll
            for (int i = 0; i < 13; ++i) {      // dz 12..24
                sZ[(12 + i) * 128 + c] = a0[i];
                sZ[(37 + i) * 128 + c] = a1[i];
            }
        }
    }
    __syncthreads();   // sZ ready; sXc dead -> sOut may alias its span

    // Stage D: linear_out, wave -> l-aligned d-range (wz read once per block)
    if      (wave == 0) d_tile<0, 4>(sZ, wzg, sOut, lane);   // l0+l1
    else if (wave == 1) d_tile<4, 5>(sZ, wzg, sOut, lane);   // l2
    else if (wave == 2) d_tile<9, 7>(sZ, wzg, sOut, lane);   // l3
    else                d_tile<16, 9>(sZ, wzg, sOut, lane);  // l4
    __syncthreads();

    // Stage E: coalesced float4 store of both nodes' outputs
    float* po = outg + 2 * b * (CH * DZ);
    const float4* so = (const float4*)sOut;
    for (int j = tid; j < (2 * CH * DZ) / 4; j += 256)
        ((float4*)po)[j] = so[j];
}

extern "C" void kernel_launch(void* const* d_in, const int* in_sizes, int n_in,
                              void* d_out, int out_size, void* d_ws, size_t ws_size,
                              hipStream_t stream) {
    static float h_gGt[81 * 28];   // zero-init pads
    static bool built = false;
    if (!built) { host_build_gaunt(h_gGt); built = true; }
    hipMemcpyAsync(d_ws, h_gGt, sizeof(h_gGt), hipMemcpyHostToDevice, stream);

    int N = in_sizes[0] / (MULT * DIN);

    hipLaunchKernelGGL(gaunt_fused, dim3(N / 2), dim3(256), 0, stream,
                       (const float*)d_in[0], (const float*)d_in[1],
                       (const float*)d_in[2], (const float*)d_in[3],
                       (const float*)d_in[4], (float*)d_out, (const float*)d_ws);
}

// Round 3
// 127.883 us; speedup vs baseline: 1.0301x; 1.0301x over previous
//
#include <hip/hip_runtime.h>
#include <cmath>

// Static problem config (matches reference)
#define RB 20
#define RA 19
#define NPT (RB*RA)
#define DZ 25
#define DIN 9
#define MULT 128
#define CH 128

// ---------------------------------------------------------------------------
// Real-Gaunt selection rules (exact): G[d1][d2][dz] can be nonzero only if
//  (1) triangle |l1-l2| <= l3 <= l1+l2, (2) parity l1+l2+l3 even,
//  (3) |m3| in {|m1|+|m2|, ||m1|-|m2||}, (4) even # of sin-type (m<0) factors.
// This is a SUPERSET of the true nonzeros (accidental zeros harmless).
// 162 of 2025 entries survive. Host zeroes the rest (they are ~1e-16
// quadrature noise), kernel skips them -> bit-exact vs dense accumulation.
__host__ __device__ constexpr int L_of(int d) { return d == 0 ? 0 : d < 4 ? 1 : d < 9 ? 2 : d < 16 ? 3 : 4; }
__host__ __device__ constexpr int M_of(int d) { return d - L_of(d) * L_of(d) - L_of(d); }
__host__ __device__ constexpr bool gz_nz(int d1, int d2, int dz) {
    const int l1 = L_of(d1), l2 = L_of(d2), l3 = L_of(dz);
    const int m1 = M_of(d1), m2 = M_of(d2), m3 = M_of(dz);
    const int lo = l1 > l2 ? l1 - l2 : l2 - l1;
    if (l3 < lo || l3 > l1 + l2) return false;
    if ((l1 + l2 + l3) & 1) return false;
    const int a1 = m1 < 0 ? -m1 : m1, a2 = m2 < 0 ? -m2 : m2, a3 = m3 < 0 ? -m3 : m3;
    const int sum = a1 + a2, dif = a1 > a2 ? a1 - a2 : a2 - a1;
    if (a3 != sum && a3 != dif) return false;
    if (((m1 < 0) + (m2 < 0) + (m3 < 0)) & 1) return false;
    return true;
}
__host__ __device__ constexpr bool pair_any(int d1, int d2) {
    for (int dz = 0; dz < DZ; ++dz) if (gz_nz(d1, d2, dz)) return true;
    return false;
}

// ---------------------------------------------------------------------------
// Host: transposed dense real-Gaunt table Gt[d1*9+d2][28] in fp64 from the
// reference's own quadrature. Cols 25..27 zero pads. Selection-rule zeros
// (~1e-16 noise) forced to exactly 0.0f so the kernel's sparse skip is exact.
static void host_build_gaunt(float* out /* 81*28, zero-padded */) {
    const double PI = 3.14159265358979323846;
    double xq[RB], wq[RB];
    for (int i = 0; i < RB; ++i) {
        double x = cos(PI * (i + 0.75) / (RB + 0.5));
        double dp = 0.0;
        for (int it = 0; it < 100; ++it) {
            double p0 = 1.0, p1 = x;
            for (int k = 2; k <= RB; ++k) {
                double p2 = ((2.0*k - 1.0)*x*p1 - (k - 1.0)*p0) / (double)k;
                p0 = p1; p1 = p2;
            }
            dp = RB * (x*p1 - p0) / (x*x - 1.0);
            double dx = p1 / dp;
            x -= dx;
            if (fabs(dx) < 1e-15) break;
        }
        {
            double p0 = 1.0, p1 = x;
            for (int k = 2; k <= RB; ++k) {
                double p2 = ((2.0*k - 1.0)*x*p1 - (k - 1.0)*p0) / (double)k;
                p0 = p1; p1 = p2;
            }
            dp = RB * (x*p1 - p0) / (x*x - 1.0);
        }
        xq[i] = x;
        wq[i] = 2.0 / ((1.0 - x*x)*dp*dp);
    }
    static double Y[DZ][NPT];
    static double qws[NPT];
    for (int b = 0; b < RB; ++b) {
        double ct = xq[b], st = sqrt(fmax(0.0, 1.0 - ct*ct));
        double P[5][5]; double pmm = 1.0;
        for (int m = 0; m <= 4; ++m) {
            if (m > 0) pmm *= -(2.0*m - 1.0) * st;
            P[m][m] = pmm;
            if (m < 4) {
                double pp = pmm, pc = ct*(2.0*m + 1.0)*pmm;
                P[m+1][m] = pc;
                for (int l = m + 2; l <= 4; ++l) {
                    double pn = ((2.0*l - 1.0)*ct*pc - (double)(l + m - 1)*pp) / (double)(l - m);
                    P[l][m] = pn; pp = pc; pc = pn;
                }
            }
        }
        for (int a = 0; a < RA; ++a) {
            int pt = b*RA + a;
            qws[pt] = wq[b] * (2.0*PI/(double)RA);
            double alpha = 2.0*PI*(double)a/(double)RA;
            for (int l = 0; l <= 4; ++l)
                for (int m = -l; m <= l; ++m) {
                    int am = m < 0 ? -m : m;
                    double fr = 1.0;
                    for (int i = l - am + 1; i <= l + am; ++i) fr *= (double)i;
                    double nlm = sqrt((2.0*l + 1.0) / (4.0*PI) / fr);
                    double ang = (m == 0) ? 1.0
                               : (m > 0 ? sqrt(2.0)*cos(am*alpha) : sqrt(2.0)*sin(am*alpha));
                    Y[l*l + l + m][pt] = nlm * P[l][am] * ang;
                }
        }
    }
    for (int pr = 0; pr < 81; ++pr) {
        int d1 = pr / 9, d2 = pr % 9;
        for (int d = 0; d < DZ; ++d) {
            double s = 0.0;
            for (int p = 0; p < NPT; ++p)
                s += Y[d][p] * Y[d1][p] * Y[d2][p] * qws[p];
            out[pr*28 + d] = gz_nz(d1, d2, d) ? (float)s : 0.0f;
        }
    }
}

// ---------------------------------------------------------------------------
// Compile-time-unrolled sparse stage C: only the 162 rule-allowed (d1,d2,dz)
// terms are emitted. Per-dz accumulation order (d1 asc, d2 asc) matches the
// dense version among nonzero terms -> bit-identical given zeroed table.
template<int D1, int D2, int DZi>
__device__ __forceinline__ void c_dz(const float* __restrict__ g, float p, float* z) {
    if constexpr (DZi < DZ) {
        if constexpr (gz_nz(D1, D2, DZi))
            z[DZi] = fmaf(p, g[(D1 * 9 + D2) * 28 + DZi], z[DZi]);
        c_dz<D1, D2, DZi + 1>(g, p, z);
    }
}
template<int D1, int D2>
__device__ __forceinline__ void c_d2(const float* __restrict__ g,
                                     const float* xr, const float* yr, float* z) {
    if constexpr (D2 < 9) {
        if constexpr (pair_any(D1, D2)) {
            const float p = xr[D1] * yr[D2];
            c_dz<D1, D2, 0>(g, p, z);
        }
        c_d2<D1, D2 + 1>(g, xr, yr, z);
    }
}
template<int D1>
__device__ __forceinline__ void c_d1(const float* __restrict__ g,
                                     const float* xr, const float* yr, float* z) {
    if constexpr (D1 < 9) {
        c_d2<D1, 0>(g, xr, yr, z);
        c_d1<D1 + 1>(g, xr, yr, z);
    }
}

// ---------------------------------------------------------------------------
// Fully fused, 2 nodes per block, 256 threads (proven R0 base; unroll-4
// everywhere -- unroll-8 spilled in R2). R3 structure:
//   A : x,y -> sXY transposed; Gaunt table -> sG            (barrier)
//   BC: thread=(node,c): xc[9],yc[9] in regs (same fma order as R0 stage B),
//       then SPARSE stage C in regs (162 terms vs 2106), z -> sZ  (barrier)
//   D : thread=(node,e): all 25 d, c-loop order identical to R0 d_tile,
//       perfectly balanced (3200 fma/thread), direct global store.
// Barriers 5 -> 2; sXc buffer and stage E deleted; no LDS aliasing needed.
__global__ __launch_bounds__(256) void gaunt_fused(
    const float* __restrict__ xg, const float* __restrict__ yg,
    const float* __restrict__ wxg, const float* __restrict__ wyg,
    const float* __restrict__ wzg, float* __restrict__ outg,
    const float* __restrict__ gGt) {

    // LDS pool (floats), 13276 = 53104 B (3 blocks/CU capacity):
    //  sZ   [0,     6400)  z [n][dz][c]        (BC writes, D reads)
    //  sXY  [6400, 11008)  x,y transposed [side][n][d*128+m]
    //  sG   [11008,13276)  Gaunt table
    __shared__ __align__(16) float pool[13276];
    float* sZ  = pool;
    float* sXY = pool + 6400;
    float* sG  = pool + 11008;

    const int tid = threadIdx.x;
    const int b   = blockIdx.x;
    const float s128 = 0.08838834764831845f;   // 1/sqrt(128)

    // Stage A: load x,y for nodes 2b,2b+1 -> transpose; Gaunt table -> sG
    {
        const float4* xs = (const float4*)(xg + 2 * b * 1152);
        const float4* ys = (const float4*)(yg + 2 * b * 1152);
        for (int i = tid; i < 1152; i += 256) {
            float4 v = (i < 576) ? xs[i] : ys[i - 576];
            int r = (i < 576) ? i : i - 576;
            int base = (i < 576) ? 0 : 2304;
            int j0 = r * 4;
            #pragma unroll
            for (int k = 0; k < 4; ++k) {
                int j = j0 + k;
                int n = j / 1152;
                int jj = j - n * 1152;
                int m = jj / 9, d = jj - 9 * m;
                float val = (k == 0) ? v.x : (k == 1) ? v.y : (k == 2) ? v.z : v.w;
                sXY[base + n * 1152 + d * 128 + m] = val;
            }
        }
        for (int i = tid; i < 567; i += 256)
            ((float4*)sG)[i] = ((const float4*)gGt)[i];
    }
    __syncthreads();

    // Stage B+C fused: thread = (node n, channel c). xc/yc stay in registers;
    // sparse Gaunt contraction immediately after; z -> sZ.
    {
        const int n = tid >> 7;            // wave-uniform (waves 0-1: n=0)
        const int c = tid & 127;
        float xr[9], yr[9];
        #pragma unroll
        for (int side = 0; side < 2; ++side) {
            const float* wb = side ? wyg : wxg;
            const float* xb = sXY + side * 2304 + n * 1152;   // [d*128+m]
            float acc[9];
            #pragma unroll
            for (int d = 0; d < 9; ++d) acc[d] = 0.f;
            for (int m0 = 0; m0 < MULT; m0 += 4) {
                float w0[4], w1[4], w2[4];
                #pragma unroll
                for (int k = 0; k < 4; ++k) {
                    w0[k] = wb[(m0 + k) * 128 + c];
                    w1[k] = wb[16384 + (m0 + k) * 128 + c];
                    w2[k] = wb[32768 + (m0 + k) * 128 + c];
                }
                #pragma unroll
                for (int d = 0; d < 9; ++d) {
                    const float* wl = (d == 0) ? w0 : (d < 4) ? w1 : w2;
                    float4 xv = *(const float4*)(xb + d * 128 + m0);  // broadcast
                    acc[d] = fmaf(xv.x, wl[0], acc[d]);
                    acc[d] = fmaf(xv.y, wl[1], acc[d]);
                    acc[d] = fmaf(xv.z, wl[2], acc[d]);
                    acc[d] = fmaf(xv.w, wl[3], acc[d]);
                }
            }
            float* dst = side ? yr : xr;
            #pragma unroll
            for (int d = 0; d < 9; ++d) dst[d] = acc[d] * s128;
        }

        float z[DZ];
        #pragma unroll
        for (int i = 0; i < DZ; ++i) z[i] = 0.f;
        c_d1<0>(sG, xr, yr, z);            // 162 sparse terms

        #pragma unroll
        for (int dz = 0; dz < DZ; ++dz)
            sZ[(n * DZ + dz) * 128 + c] = z[dz];
    }
    __syncthreads();

    // Stage D: linear_out. thread = (node n, channel e); all 25 d per thread
    // (balanced); per-output c-order identical to R0's d_tile (c0 asc, k asc).
    {
        const int n = tid >> 7;            // wave-uniform
        const int e = tid & 127;
        const float* zb = sZ + n * DZ * 128;
        float acc[DZ];
        #pragma unroll
        for (int d = 0; d < DZ; ++d) acc[d] = 0.f;
        for (int c0 = 0; c0 < CH; c0 += 4) {
            float w[5][4];
            #pragma unroll
            for (int l = 0; l < 5; ++l)
                #pragma unroll
                for (int k = 0; k < 4; ++k)
                    w[l][k] = wzg[l * 16384 + (c0 + k) * 128 + e];
            #pragma unroll
            for (int d = 0; d < DZ; ++d) {
                const int l = (d == 0) ? 0 : (d < 4) ? 1 : (d < 9) ? 2 : (d < 16) ? 3 : 4;
                float4 z4 = *(const float4*)(zb + d * 128 + c0);      // broadcast
                acc[d] = fmaf(z4.x, w[l][0], acc[d]);
                acc[d] = fmaf(z4.y, w[l][1], acc[d]);
                acc[d] = fmaf(z4.z, w[l][2], acc[d]);
                acc[d] = fmaf(z4.w, w[l][3], acc[d]);
            }
        }
        float* po = outg + ((size_t)(2 * b + n) * 128 + e) * DZ;      // 100 B/thread
        #pragma unroll
        for (int d = 0; d < DZ; ++d) po[d] = acc[d] * s128;
    }
}

extern "C" void kernel_launch(void* const* d_in, const int* in_sizes, int n_in,
                              void* d_out, int out_size, void* d_ws, size_t ws_size,
                              hipStream_t stream) {
    static float h_gGt[81 * 28];   // zero-init pads
    static bool built = false;
    if (!built) { host_build_gaunt(h_gGt); built = true; }
    hipMemcpyAsync(d_ws, h_gGt, sizeof(h_gGt), hipMemcpyHostToDevice, stream);

    int N = in_sizes[0] / (MULT * DIN);

    hipLaunchKernelGGL(gaunt_fused, dim3(N / 2), dim3(256), 0, stream,
                       (const float*)d_in[0], (const float*)d_in[1],
                       (const float*)d_in[2], (const float*)d_in[3],
                       (const float*)d_in[4], (float*)d_out, (const float*)d_ws);
}

// Round 4
// 108.135 us; speedup vs baseline: 1.2182x; 1.1826x over previous
//
#include <hip/hip_runtime.h>
#include <cmath>

// Static problem config (matches reference)
#define RB 20
#define RA 19
#define NPT (RB*RA)
#define DZ 25
#define DIN 9
#define MULT 128
#define CH 128

// ---------------------------------------------------------------------------
// Real-Gaunt selection rules (exact superset of nonzeros; verified R3: same
// absmax as dense). 162 of 2025 (d1,d2,dz) entries survive.
__host__ __device__ constexpr int L_of(int d) { return d == 0 ? 0 : d < 4 ? 1 : d < 9 ? 2 : d < 16 ? 3 : 4; }
__host__ __device__ constexpr int M_of(int d) { return d - L_of(d) * L_of(d) - L_of(d); }
__host__ __device__ constexpr bool gz_nz(int d1, int d2, int dz) {
    const int l1 = L_of(d1), l2 = L_of(d2), l3 = L_of(dz);
    const int m1 = M_of(d1), m2 = M_of(d2), m3 = M_of(dz);
    const int lo = l1 > l2 ? l1 - l2 : l2 - l1;
    if (l3 < lo || l3 > l1 + l2) return false;
    if ((l1 + l2 + l3) & 1) return false;
    const int a1 = m1 < 0 ? -m1 : m1, a2 = m2 < 0 ? -m2 : m2, a3 = m3 < 0 ? -m3 : m3;
    const int sum = a1 + a2, dif = a1 > a2 ? a1 - a2 : a2 - a1;
    if (a3 != sum && a3 != dif) return false;
    if (((m1 < 0) + (m2 < 0) + (m3 < 0)) & 1) return false;
    return true;
}
template<int DZ0, int DZ1>
__host__ __device__ constexpr bool pair_any_r(int d1, int d2) {
    for (int dz = DZ0; dz < DZ1; ++dz) if (gz_nz(d1, d2, dz)) return true;
    return false;
}

// ---------------------------------------------------------------------------
// Host: transposed dense real-Gaunt table Gt[d1*9+d2][28] in fp64 from the
// reference's own quadrature. Cols 25..27 zero pads. Rule-zero entries
// (~1e-16 quadrature noise) forced to exactly 0.0f.
static void host_build_gaunt(float* out /* 81*28, zero-padded */) {
    const double PI = 3.14159265358979323846;
    double xq[RB], wq[RB];
    for (int i = 0; i < RB; ++i) {
        double x = cos(PI * (i + 0.75) / (RB + 0.5));
        double dp = 0.0;
        for (int it = 0; it < 100; ++it) {
            double p0 = 1.0, p1 = x;
            for (int k = 2; k <= RB; ++k) {
                double p2 = ((2.0*k - 1.0)*x*p1 - (k - 1.0)*p0) / (double)k;
                p0 = p1; p1 = p2;
            }
            dp = RB * (x*p1 - p0) / (x*x - 1.0);
            double dx = p1 / dp;
            x -= dx;
            if (fabs(dx) < 1e-15) break;
        }
        {
            double p0 = 1.0, p1 = x;
            for (int k = 2; k <= RB; ++k) {
                double p2 = ((2.0*k - 1.0)*x*p1 - (k - 1.0)*p0) / (double)k;
                p0 = p1; p1 = p2;
            }
            dp = RB * (x*p1 - p0) / (x*x - 1.0);
        }
        xq[i] = x;
        wq[i] = 2.0 / ((1.0 - x*x)*dp*dp);
    }
    static double Y[DZ][NPT];
    static double qws[NPT];
    for (int b = 0; b < RB; ++b) {
        double ct = xq[b], st = sqrt(fmax(0.0, 1.0 - ct*ct));
        double P[5][5]; double pmm = 1.0;
        for (int m = 0; m <= 4; ++m) {
            if (m > 0) pmm *= -(2.0*m - 1.0) * st;
            P[m][m] = pmm;
            if (m < 4) {
                double pp = pmm, pc = ct*(2.0*m + 1.0)*pmm;
                P[m+1][m] = pc;
                for (int l = m + 2; l <= 4; ++l) {
                    double pn = ((2.0*l - 1.0)*ct*pc - (double)(l + m - 1)*pp) / (double)(l - m);
                    P[l][m] = pn; pp = pc; pc = pn;
                }
            }
        }
        for (int a = 0; a < RA; ++a) {
            int pt = b*RA + a;
            qws[pt] = wq[b] * (2.0*PI/(double)RA);
            double alpha = 2.0*PI*(double)a/(double)RA;
            for (int l = 0; l <= 4; ++l)
                for (int m = -l; m <= l; ++m) {
                    int am = m < 0 ? -m : m;
                    double fr = 1.0;
                    for (int i = l - am + 1; i <= l + am; ++i) fr *= (double)i;
                    double nlm = sqrt((2.0*l + 1.0) / (4.0*PI) / fr);
                    double ang = (m == 0) ? 1.0
                               : (m > 0 ? sqrt(2.0)*cos(am*alpha) : sqrt(2.0)*sin(am*alpha));
                    Y[l*l + l + m][pt] = nlm * P[l][am] * ang;
                }
        }
    }
    for (int pr = 0; pr < 81; ++pr) {
        int d1 = pr / 9, d2 = pr % 9;
        for (int d = 0; d < DZ; ++d) {
            double s = 0.0;
            for (int p = 0; p < NPT; ++p)
                s += Y[d][p] * Y[d1][p] * Y[d2][p] * qws[p];
            out[pr*28 + d] = gz_nz(d1, d2, d) ? (float)s : 0.0f;
        }
    }
}

// ---------------------------------------------------------------------------
// Sparse stage C, compile-time unrolled over the thread's dz range [DZ0,DZ1).
// Same (d1 asc, d2 asc, dz asc) accumulation order as R0's dense loop among
// nonzero terms -> bit-identical (fmaf(p, 0.0f, a) == a for the skipped).
template<int DZ0, int DZ1, int D1, int D2, int DZi>
__device__ __forceinline__ void c_dz(const float* __restrict__ g, float p0, float p1,
                                     float* a0, float* a1) {
    if constexpr (DZi < DZ1) {
        if constexpr (gz_nz(D1, D2, DZi)) {
            const float gv = g[(D1 * 9 + D2) * 28 + DZi];   // b32 broadcast
            a0[DZi - DZ0] = fmaf(p0, gv, a0[DZi - DZ0]);
            a1[DZi - DZ0] = fmaf(p1, gv, a1[DZi - DZ0]);
        }
        c_dz<DZ0, DZ1, D1, D2, DZi + 1>(g, p0, p1, a0, a1);
    }
}
template<int DZ0, int DZ1, int D1, int D2>
__device__ __forceinline__ void c_d2(const float* __restrict__ g,
                                     const float* x0, const float* x1,
                                     const float* y0, const float* y1,
                                     float* a0, float* a1) {
    if constexpr (D2 < 9) {
        if constexpr (pair_any_r<DZ0, DZ1>(D1, D2))
            c_dz<DZ0, DZ1, D1, D2, DZ0>(g, x0[D1] * y0[D2], x1[D1] * y1[D2], a0, a1);
        c_d2<DZ0, DZ1, D1, D2 + 1>(g, x0, x1, y0, y1, a0, a1);
    }
}
template<int DZ0, int DZ1, int D1>
__device__ __forceinline__ void c_d1(const float* __restrict__ g,
                                     const float* x0, const float* x1,
                                     const float* y0, const float* y1,
                                     float* a0, float* a1) {
    if constexpr (D1 < 9) {
        c_d2<DZ0, DZ1, D1, 0>(g, x0, x1, y0, y1, a0, a1);
        c_d1<DZ0, DZ1, D1 + 1>(g, x0, x1, y0, y1, a0, a1);
    }
}

// ---------------------------------------------------------------------------
// Stage D helper (R0's proven mapping, unroll-4): wave owns l-aligned d-range
// [D0,D0+ND) so wz_l columns are read once per block; lane owns e=lane and
// e+64; both nodes. Stores go DIRECTLY to global (no sOut/stage E/barrier);
// the block fully covers its contiguous 25.6 KB out region, so L2 merges.
template<int D0, int ND>
__device__ __forceinline__ void d_tile(const float* sZ, const float* __restrict__ wz,
                                       float* __restrict__ po, int lane) {
    const float s128 = 0.08838834764831845f;
    float acc[ND * 4];
    #pragma unroll
    for (int i = 0; i < ND * 4; ++i) acc[i] = 0.f;
    for (int c0 = 0; c0 < CH; c0 += 4) {
        #pragma unroll
        for (int i = 0; i < ND; ++i) {
            const int d = D0 + i;
            const int l = (d == 0) ? 0 : (d < 4) ? 1 : (d < 9) ? 2 : (d < 16) ? 3 : 4;
            float4 z0 = *(const float4*)(sZ + d * 128 + c0);          // node0 broadcast
            float4 z1 = *(const float4*)(sZ + (25 + d) * 128 + c0);   // node1 broadcast
            #pragma unroll
            for (int k = 0; k < 4; ++k) {
                float wa = wz[l * 16384 + (c0 + k) * 128 + lane];       // CSE across same-l i
                float wb = wz[l * 16384 + (c0 + k) * 128 + lane + 64];
                float zc0 = (k == 0) ? z0.x : (k == 1) ? z0.y : (k == 2) ? z0.z : z0.w;
                float zc1 = (k == 0) ? z1.x : (k == 1) ? z1.y : (k == 2) ? z1.z : z1.w;
                acc[i*4+0] = fmaf(zc0, wa, acc[i*4+0]);
                acc[i*4+1] = fmaf(zc0, wb, acc[i*4+1]);
                acc[i*4+2] = fmaf(zc1, wa, acc[i*4+2]);
                acc[i*4+3] = fmaf(zc1, wb, acc[i*4+3]);
            }
        }
    }
    #pragma unroll
    for (int i = 0; i < ND; ++i) {
        po[lane * 25 + D0 + i]               = acc[i*4+0] * s128;
        po[(lane + 64) * 25 + D0 + i]        = acc[i*4+1] * s128;
        po[3200 + lane * 25 + D0 + i]        = acc[i*4+2] * s128;
        po[3200 + (lane + 64) * 25 + D0 + i] = acc[i*4+3] * s128;
    }
}

// ---------------------------------------------------------------------------
// Fully fused, 2 nodes per block, 256 threads. R0's proven thread mappings
// (they minimize global-load instructions: node-pair shares w in B, wave-per-l
// shares wz in D -- R1/R3 showed breaking either doubles VMEM and regresses).
// R4 subtractive deltas: G loaded in stage A (no B2 stage/barrier); sparse
// stage C (162 terms vs 2106, same order -> bit-exact); stage D stores direct
// to global (no sOut, no stage E, no final barrier). Barriers 5 -> 3.
__global__ __launch_bounds__(256) void gaunt_fused(
    const float* __restrict__ xg, const float* __restrict__ yg,
    const float* __restrict__ wxg, const float* __restrict__ wyg,
    const float* __restrict__ wzg, float* __restrict__ outg,
    const float* __restrict__ gGt) {

    // LDS pool (floats), 17884 = 71536 B (2 blocks/CU: 143072 <= 163840;
    // grid 512 on 256 CUs caps residency at 2 blocks/CU anyway):
    //  sZ   [0,     6400)  z [n][dz][c]                 (C writes, D reads)
    //  sXY  [6400, 11008)  x,y transposed [side][n][d*128+m]  (A/B)
    //  sXc  [11008,15616)  xc [side][d][n][c]           (B/C)
    //  sG   [15616,17884)  Gaunt table                  (loaded A, read C)
    __shared__ __align__(16) float pool[17884];
    float* sZ  = pool;
    float* sXY = pool + 6400;
    float* sXc = pool + 11008;
    float* sG  = pool + 15616;

    const int tid  = threadIdx.x;
    const int b    = blockIdx.x;
    const int lane = tid & 63;
    const int wave = __builtin_amdgcn_readfirstlane(tid >> 6);
    const float s128 = 0.08838834764831845f;   // 1/sqrt(128)

    // Stage A: x,y for nodes 2b,2b+1 -> transposed sXY; Gaunt table -> sG
    {
        const float4* xs = (const float4*)(xg + 2 * b * 1152);
        const float4* ys = (const float4*)(yg + 2 * b * 1152);
        for (int i = tid; i < 1152; i += 256) {
            float4 v = (i < 576) ? xs[i] : ys[i - 576];
            int r = (i < 576) ? i : i - 576;
            int base = (i < 576) ? 0 : 2304;
            int j0 = r * 4;
            #pragma unroll
            for (int k = 0; k < 4; ++k) {
                int j = j0 + k;
                int n = j / 1152;
                int jj = j - n * 1152;
                int m = jj / 9, d = jj - 9 * m;
                float val = (k == 0) ? v.x : (k == 1) ? v.y : (k == 2) ? v.z : v.w;
                sXY[base + n * 1152 + d * 128 + m] = val;
            }
        }
        for (int i = tid; i < 567; i += 256)
            ((float4*)sG)[i] = ((const float4*)gGt)[i];
    }
    __syncthreads();

    // Stage B: linear_in (R0 verbatim). wave=(side,chalf), lane owns one c;
    // both nodes share each w fetch. Unroll-4 (unroll-8 spilled in R2).
    {
        const int side = wave >> 1, ch = wave & 1;
        const int c = ch * 64 + lane;
        const float* wb = side ? wyg : wxg;
        const float* xb = sXY + side * 2304;   // [n][d*128+m]
        float acc[18];                          // [d][n]
        #pragma unroll
        for (int i = 0; i < 18; ++i) acc[i] = 0.f;
        for (int m0 = 0; m0 < MULT; m0 += 4) {
            float w0[4], w1[4], w2[4];
            #pragma unroll
            for (int k = 0; k < 4; ++k) {
                w0[k] = wb[(m0 + k) * 128 + c];
                w1[k] = wb[16384 + (m0 + k) * 128 + c];
                w2[k] = wb[32768 + (m0 + k) * 128 + c];
            }
            #pragma unroll
            for (int d = 0; d < 9; ++d) {
                const float* wl = (d == 0) ? w0 : (d < 4) ? w1 : w2;
                float4 x0 = *(const float4*)(xb + d * 128 + m0);
                float4 x1 = *(const float4*)(xb + 1152 + d * 128 + m0);
                acc[d*2+0] = fmaf(x0.x, wl[0], acc[d*2+0]);
                acc[d*2+0] = fmaf(x0.y, wl[1], acc[d*2+0]);
                acc[d*2+0] = fmaf(x0.z, wl[2], acc[d*2+0]);
                acc[d*2+0] = fmaf(x0.w, wl[3], acc[d*2+0]);
                acc[d*2+1] = fmaf(x1.x, wl[0], acc[d*2+1]);
                acc[d*2+1] = fmaf(x1.y, wl[1], acc[d*2+1]);
                acc[d*2+1] = fmaf(x1.z, wl[2], acc[d*2+1]);
                acc[d*2+1] = fmaf(x1.w, wl[3], acc[d*2+1]);
            }
        }
        #pragma unroll
        for (int d = 0; d < 9; ++d) {
            sXc[((side * 9 + d) * 2 + 0) * 128 + c] = acc[d*2+0] * s128;
            sXc[((side * 9 + d) * 2 + 1) * 128 + c] = acc[d*2+1] * s128;
        }
    }
    __syncthreads();

    // Stage C: SPARSE z = G : (xc o yc). R0's exact mapping: thread=(c,
    // dz-half), both nodes; only the 162 rule-allowed terms are emitted.
    {
        const int c = tid & 127;
        const int half = __builtin_amdgcn_readfirstlane(tid >> 7);
        float xr0[9], xr1[9], yr0[9], yr1[9];
        #pragma unroll
        for (int d = 0; d < 9; ++d) {
            xr0[d] = sXc[(d * 2 + 0) * 128 + c];
            xr1[d] = sXc[(d * 2 + 1) * 128 + c];
            yr0[d] = sXc[((9 + d) * 2 + 0) * 128 + c];
            yr1[d] = sXc[((9 + d) * 2 + 1) * 128 + c];
        }
        if (half == 0) {
            float a0[12], a1[12];
            #pragma unroll
            for (int i = 0; i < 12; ++i) { a0[i] = 0.f; a1[i] = 0.f; }
            c_d1<0, 12, 0>(sG, xr0, xr1, yr0, yr1, a0, a1);
            #pragma unroll
            for (int i = 0; i < 12; ++i) {      // dz 0..11
                sZ[i * 128 + c]        = a0[i];
                sZ[(25 + i) * 128 + c] = a1[i];
            }
        } else {
            float a0[13], a1[13];
            #pragma unroll
            for (int i = 0; i < 13; ++i) { a0[i] = 0.f; a1[i] = 0.f; }
            c_d1<12, 25, 0>(sG, xr0, xr1, yr0, yr1, a0, a1);
            #pragma unroll
            for (int i = 0; i < 13; ++i) {      // dz 12..24
                sZ[(12 + i) * 128 + c] = a0[i];
                sZ[(37 + i) * 128 + c] = a1[i];
            }
        }
    }
    __syncthreads();

    // Stage D: linear_out, wave -> l-aligned d-range, direct global stores.
    // No final barrier: waves retire independently (l4 imbalance overlaps
    // with the co-resident block).
    float* po = outg + 2 * b * (CH * DZ);
    if      (wave == 0) d_tile<0, 4>(sZ, wzg, po, lane);   // l0+l1
    else if (wave == 1) d_tile<4, 5>(sZ, wzg, po, lane);   // l2
    else if (wave == 2) d_tile<9, 7>(sZ, wzg, po, lane);   // l3
    else                d_tile<16, 9>(sZ, wzg, po, lane);  // l4
}

extern "C" void kernel_launch(void* const* d_in, const int* in_sizes, int n_in,
                              void* d_out, int out_size, void* d_ws, size_t ws_size,
                              hipStream_t stream) {
    static float h_gGt[81 * 28];   // zero-init pads
    static bool built = false;
    if (!built) { host_build_gaunt(h_gGt); built = true; }
    hipMemcpyAsync(d_ws, h_gGt, sizeof(h_gGt), hipMemcpyHostToDevice, stream);

    int N = in_sizes[0] / (MULT * DIN);

    hipLaunchKernelGGL(gaunt_fused, dim3(N / 2), dim3(256), 0, stream,
                       (const float*)d_in[0], (const float*)d_in[1],
                       (const float*)d_in[2], (const float*)d_in[3],
                       (const float*)d_in[4], (float*)d_out, (const float*)d_ws);
}